// Round 10
// baseline (122.871 us; speedup 1.0000x reference)
//
#include <hip/hip_runtime.h>
#include <hip/hip_bf16.h>
#include <stdint.h>
#include <stddef.h>

// MMD via single signed 2N x 2N RBF gram, lower triangle only.
// Round 10: MX-fp8 (16x16x128, unit scales) + 128x64 block tiles.
// Wave tile 64x32 -> acc 32 AGPR (was 64), af 64, a_i in LDS: ~140 live regs
// <= 170 cap -> launch_bounds(256,3) without spill (r7/r8 failed at acc=64).
// LDS: two 16 KB B buffers (33 KB) -> 3 blocks/CU = 3 waves/SIMD (+50% TLP
// over r9's 2). Triangle at 64-col granularity: strip br has col-tiles
// bc64 in [0, 2br+1]; weight 2 if bc64 < 2br else 1 (two diag tiles = the
// full 128x128 diagonal block summed once).

#define N_PTS   8192
#define DIM     256
#define TWO_N   16384
#define CS2     16

#define AS1 __attribute__((address_space(1)))
#define AS3 __attribute__((address_space(3)))

typedef __attribute__((ext_vector_type(4))) float f32x4;
typedef __attribute__((ext_vector_type(4))) int   i32x4;
typedef __attribute__((ext_vector_type(8))) int   i32x8;

// ---------------------------------------------------------------------------
// Prep: fp32 -> fp8 e4m3 (row-major) + c2-scaled fp32 row norms + zero output.
// n2[row] = c2 * |z_row|^2, c2 = -log2e/sigma (epilogue adds directly).
// ---------------------------------------------------------------------------
__global__ __launch_bounds__(256) void mmd_prep(const float* __restrict__ X,
                                                const float* __restrict__ Y,
                                                const int* __restrict__ sigmap,
                                                unsigned char* __restrict__ Zf8,
                                                float* __restrict__ n2,
                                                float* __restrict__ out) {
    if (blockIdx.x == 0 && threadIdx.x == 0) out[0] = 0.0f;

    const int wave = threadIdx.x >> 6;
    const int lane = threadIdx.x & 63;
    const int row  = blockIdx.x * 4 + wave;          // 0 .. TWO_N-1

    const float* src = (row < N_PTS) ? (X + (size_t)row * DIM)
                                     : (Y + (size_t)(row - N_PTS) * DIM);
    float4 v = ((const float4*)src)[lane];           // 64 lanes x 4 = 256

    float s = v.x * v.x + v.y * v.y + v.z * v.z + v.w * v.w;
#pragma unroll
    for (int off = 32; off; off >>= 1) s += __shfl_down(s, off, 64);
    if (lane == 0) {
        const float c2 = -1.4426950408889634f / (float)(*sigmap);
        n2[row] = c2 * s;
    }

    const int p01 = __builtin_amdgcn_cvt_pk_fp8_f32(v.x, v.y, 0, false);
    const int p23 = __builtin_amdgcn_cvt_pk_fp8_f32(v.z, v.w, 0, false);
    const unsigned int pk = ((unsigned)p01 & 0xffffu) | ((unsigned)p23 << 16);
    *(unsigned int*)(Zf8 + (size_t)row * DIM + (size_t)lane * 4) = pk;
}

// ---------------------------------------------------------------------------
// Main. grid = 128*CS2; br = 127 - (bid>>4) (heavy first), cs = bid & 15.
// Block (br,cs) processes 128x64 tiles bc64 = cs, cs+16, ... <= 2*br+1.
// 4 waves in 2x2 over 128x64: wave (wm,wn) owns 64 rows x 32 cols =
// 4(mt) x 2(nt) MFMA tiles of 16x16x128 MX-fp8 (2 k-chunks each).
// A frags (full K=256, 64 VGPRs) stationary; B (16 KB) ping-pong buffered.
// ---------------------------------------------------------------------------
__global__ __launch_bounds__(256, 3) void mmd_main(const unsigned char* __restrict__ Zf8,
                                                   const float* __restrict__ n2,
                                                   const int* __restrict__ sigmap,
                                                   float* __restrict__ out) {
    __shared__ char smem_b[32768];   // 2 x 16 KB B-tile buffers, XOR swizzle
    __shared__ float n2rS[128];      // c2*|z|^2 for this block's 128 rows
    __shared__ float wsum[4];

    const int bid = (int)blockIdx.x;
    const int br  = 127 - (bid >> 4);
    const int cs  = bid & (CS2 - 1);
    const int bcMax = 2 * br + 1;
    if (cs > bcMax) return;

    const int t    = threadIdx.x;
    const int wave = t >> 6;
    const int lane = t & 63;
    const int wm   = wave >> 1;      // row half (64)
    const int wn   = wave & 1;       // col half (32)
    const int g    = lane >> 4;      // k-quad
    const int ml   = lane & 15;
    const int rowBase = br * 128;

    const float m2 = 2.8853900817779268f / (float)(*sigmap);   // -2*c2
    const int   SC = 0x7f7f7f7f;     // E8M0 unit scales (2^0)

    // ---- stage B tile 0 into buffer 0 (overlaps A-frag loads below) ----
    {
        const int colBase0 = cs * 64;
#pragma unroll
        for (int i = 0; i < 4; ++i) {
            const int cidx = i * 256 + t;            // 0..1023 16B-chunks
            const int col  = cidx >> 4;              // col 0..63
            const int s    = cidx & 15;              // LDS slot
            const int gc   = s ^ (col & 15);         // XOR swizzle on source chunk
            const unsigned char* gp = Zf8 + (size_t)(colBase0 + col) * DIM + gc * 16;
            __builtin_amdgcn_global_load_lds((const AS1 void*)gp,
                                             (AS3 void*)(smem_b + (size_t)cidx * 16), 16, 0, 0);
        }
    }
    if (t < 128) n2rS[t] = n2[rowBase + t];          // row norms -> LDS

    // ---- A fragments (full K, this wave's 64 rows): 64 VGPRs ----
    i32x8 af[4][2];
#pragma unroll
    for (int mt = 0; mt < 4; ++mt) {
        const unsigned char* rp =
            Zf8 + (size_t)(rowBase + wm * 64 + mt * 16 + ml) * DIM + g * 32;
#pragma unroll
        for (int kc = 0; kc < 2; ++kc) {
            union { i32x4 h[2]; i32x8 v; } u;
            u.h[0] = *(const i32x4*)(rp + kc * 128);
            u.h[1] = *(const i32x4*)(rp + kc * 128 + 16);
            af[mt][kc] = u.v;
        }
    }

    float block_acc = 0.0f;
    const int brX = (br < 64);
    int cur = 0;

    for (int bc = cs; bc <= bcMax; bc += CS2) {
        const int colBase = bc * 64;

        float b_j[2];
#pragma unroll
        for (int nt = 0; nt < 2; ++nt)
            b_j[nt] = n2[colBase + wn * 32 + nt * 16 + ml];

        f32x4 acc[4][2] = {};

        __syncthreads();             // current buffer staged; other buffer free

        // ---- stage NEXT tile into the other buffer (overlaps compute) ----
        if (bc + CS2 <= bcMax) {
            const int colBaseN = colBase + CS2 * 64;
            char* dst = smem_b + (cur ^ 1) * 16384;
#pragma unroll
            for (int i = 0; i < 4; ++i) {
                const int cidx = i * 256 + t;
                const int col  = cidx >> 4;
                const int s    = cidx & 15;
                const int gc   = s ^ (col & 15);
                const unsigned char* gp = Zf8 + (size_t)(colBaseN + col) * DIM + gc * 16;
                __builtin_amdgcn_global_load_lds((const AS1 void*)gp,
                                                 (AS3 void*)(dst + (size_t)cidx * 16), 16, 0, 0);
            }
        }

        // ---- compute: 2 k-chunks of K=128, 4x2 MFMA each ----
        const char* buf = smem_b + cur * 16384;
#pragma unroll
        for (int kc = 0; kc < 2; ++kc) {
            const int j0 = kc * 8 + g * 2;           // first 16B chunk of lane's 32B
            i32x8 bf[2];
#pragma unroll
            for (int nt = 0; nt < 2; ++nt) {
                const int col = wn * 32 + nt * 16 + ml;
                const char* cb = buf + (size_t)col * 256;
                union { i32x4 h[2]; i32x8 v; } u;
                u.h[0] = *(const i32x4*)(cb + (size_t)((j0)     ^ (col & 15)) * 16);
                u.h[1] = *(const i32x4*)(cb + (size_t)((j0 + 1) ^ (col & 15)) * 16);
                bf[nt] = u.v;
            }
#pragma unroll
            for (int mt = 0; mt < 4; ++mt)
#pragma unroll
                for (int nt = 0; nt < 2; ++nt)
                    acc[mt][nt] = __builtin_amdgcn_mfma_scale_f32_16x16x128_f8f6f4(
                        af[mt][kc], bf[nt], acc[mt][nt],
                        0, 0,              // cbsz: fp8 A, blgp: fp8 B
                        0, SC,             // scale A: unit
                        0, SC);            // scale B: unit
        }

        // ---- epilogue: sum exp2(c2*n2i + c2*n2j + m2*dot), weighted ----
        float ts0 = 0.0f, ts1 = 0.0f, ts2 = 0.0f, ts3 = 0.0f;
#pragma unroll
        for (int mt = 0; mt < 4; ++mt) {
            const f32x4 ar = *(const f32x4*)&n2rS[wm * 64 + mt * 16 + g * 4];
#pragma unroll
            for (int nt = 0; nt < 2; ++nt) {
                const float ab = b_j[nt];
                ts0 += __builtin_amdgcn_exp2f(fmaf(acc[mt][nt][0], m2, ar[0] + ab));
                ts1 += __builtin_amdgcn_exp2f(fmaf(acc[mt][nt][1], m2, ar[1] + ab));
                ts2 += __builtin_amdgcn_exp2f(fmaf(acc[mt][nt][2], m2, ar[2] + ab));
                ts3 += __builtin_amdgcn_exp2f(fmaf(acc[mt][nt][3], m2, ar[3] + ab));
            }
        }
        const float tsum = (ts0 + ts1) + (ts2 + ts3);

        const float sgn = ((bc < 128) == brX) ? 1.0f : -1.0f;
        const float w   = (bc < 2 * br) ? 2.0f * sgn : sgn;   // diag tiles: 1x
        block_acc = fmaf(w, tsum, block_acc);
        cur ^= 1;
    }

    // ---- block reduction + single atomic ----
    float s = block_acc;
#pragma unroll
    for (int off = 32; off; off >>= 1) s += __shfl_down(s, off, 64);
    if (lane == 0) wsum[wave] = s;
    __syncthreads();
    if (t == 0)
        atomicAdd(out, (wsum[0] + wsum[1] + wsum[2] + wsum[3]) * (1.0f / 67108864.0f));
}

// ---------------------------------------------------------------------------
extern "C" void kernel_launch(void* const* d_in, const int* in_sizes, int n_in,
                              void* d_out, int out_size, void* d_ws, size_t ws_size,
                              hipStream_t stream) {
    const float* X      = (const float*)d_in[0];
    const float* Y      = (const float*)d_in[1];
    const int*   sigmap = (const int*)d_in[2];
    float*       out    = (float*)d_out;

    unsigned char* Zf8 = (unsigned char*)d_ws;                        // 4 MB
    float*         n2  = (float*)((char*)d_ws + (size_t)TWO_N * DIM);

    mmd_prep<<<TWO_N / 4, 256, 0, stream>>>(X, Y, sigmap, Zf8, n2, out);
    mmd_main<<<128 * CS2, 256, 0, stream>>>(Zf8, n2, sigmap, out);
}